// Round 3
// baseline (64208.179 us; speedup 1.0000x reference)
//
#include <hip/hip_runtime.h>
#include <cstdint>

typedef unsigned short ushortT;
typedef __attribute__((ext_vector_type(8))) short s8v;   // 8 bf16 (4 VGPRs)
typedef __attribute__((ext_vector_type(4))) float f4v;   // MFMA acc

#define B_  32
#define TIN 400
#define TOUT 500

// ---------------- threefry2x32 (JAX, 20 rounds) ----------------
__host__ __device__ __forceinline__ uint32_t rotl32(uint32_t v, int r){ return (v<<r)|(v>>(32-r)); }
__host__ __device__ inline void tf2x32(uint32_t k0, uint32_t k1, uint32_t x0, uint32_t x1,
                                       uint32_t* o0, uint32_t* o1){
  uint32_t ks2 = k0 ^ k1 ^ 0x1BD11BDAu;
  x0 += k0; x1 += k1;
  x0+=x1; x1=rotl32(x1,13); x1^=x0;  x0+=x1; x1=rotl32(x1,15); x1^=x0;
  x0+=x1; x1=rotl32(x1,26); x1^=x0;  x0+=x1; x1=rotl32(x1, 6); x1^=x0;
  x0+=k1; x1+=ks2+1u;
  x0+=x1; x1=rotl32(x1,17); x1^=x0;  x0+=x1; x1=rotl32(x1,29); x1^=x0;
  x0+=x1; x1=rotl32(x1,16); x1^=x0;  x0+=x1; x1=rotl32(x1,24); x1^=x0;
  x0+=ks2; x1+=k0+2u;
  x0+=x1; x1=rotl32(x1,13); x1^=x0;  x0+=x1; x1=rotl32(x1,15); x1^=x0;
  x0+=x1; x1=rotl32(x1,26); x1^=x0;  x0+=x1; x1=rotl32(x1, 6); x1^=x0;
  x0+=k0; x1+=k1+3u;
  x0+=x1; x1=rotl32(x1,17); x1^=x0;  x0+=x1; x1=rotl32(x1,29); x1^=x0;
  x0+=x1; x1=rotl32(x1,16); x1^=x0;  x0+=x1; x1=rotl32(x1,24); x1^=x0;
  x0+=k1; x1+=ks2+4u;
  x0+=x1; x1=rotl32(x1,13); x1^=x0;  x0+=x1; x1=rotl32(x1,15); x1^=x0;
  x0+=x1; x1=rotl32(x1,26); x1^=x0;  x0+=x1; x1=rotl32(x1, 6); x1^=x0;
  x0+=ks2; x1+=k0+5u;
  *o0 = x0; *o1 = x1;
}
// JAX partitionable random_bits (32-bit, n < 2^32): counter = (0, i), fold = o0 ^ o1
__device__ __forceinline__ float part_unif(uint32_t ka, uint32_t kb, uint32_t idx){
  uint32_t o0,o1; tf2x32(ka,kb,0u,idx,&o0,&o1);
  uint32_t bits = o0 ^ o1;
  return __uint_as_float(0x3f800000u | (bits>>9)) - 1.0f;
}

// ---------------- helpers ----------------
__device__ __forceinline__ float bf2f(ushortT u){ return __uint_as_float(((uint32_t)u)<<16); }
__device__ __forceinline__ ushortT f2bf(float f){
  uint32_t x = __float_as_uint(f);
  return (ushortT)((x + 0x7fffu + ((x>>16)&1u)) >> 16);
}
__device__ __forceinline__ float sigm(float x){ return 1.0f/(1.0f+__expf(-x)); }
__device__ __forceinline__ f4v mfma16(s8v a, s8v b, f4v c){
  return __builtin_amdgcn_mfma_f32_16x16x32_bf16(a,b,c,0,0,0);
}
__device__ __forceinline__ s8v pack8(const float* p){
  s8v r;
  #pragma unroll
  for (int j=0;j<8;++j) r[j]=(short)f2bf(p[j]);
  return r;
}

// ---------------- setup: fp32->bf16 weight copies + zero states ----------------
__global__ __launch_bounds__(256) void k_setup(
  const float* __restrict__ awih, const float* __restrict__ awhh,
  const float* __restrict__ dwih, const float* __restrict__ dwhh,
  const float* __restrict__ pjw,  const float* __restrict__ gw,
  ushortT* __restrict__ Wai, ushortT* __restrict__ Wah,
  ushortT* __restrict__ Wdi, ushortT* __restrict__ Wdh,
  ushortT* __restrict__ Wpg,
  ushortT* __restrict__ AH0, ushortT* __restrict__ AH1,
  ushortT* __restrict__ DH0, ushortT* __restrict__ DH1,
  ushortT* __restrict__ CTX,
  float* __restrict__ ac, float* __restrict__ dc,
  float* __restrict__ aw, float* __restrict__ awc)
{
  int stride = gridDim.x*blockDim.x;
  int g0 = blockIdx.x*blockDim.x + threadIdx.x;
  for (int i=g0; i<4096*768;  i+=stride) Wai[i]=f2bf(awih[i]);
  for (int i=g0; i<4096*1024; i+=stride) Wah[i]=f2bf(awhh[i]);
  for (int i=g0; i<4096*1536; i+=stride) Wdi[i]=f2bf(dwih[i]);
  for (int i=g0; i<4096*1024; i+=stride) Wdh[i]=f2bf(dwhh[i]);
  for (int i=g0; i<96*1536; i+=stride){
    int r=i/1536, k=i-r*1536;
    ushortT v=0;
    if (r<80) v=f2bf(pjw[r*1536+k]);
    else if (r==80) v=f2bf(gw[k]);
    Wpg[i]=v;
  }
  for (int i=g0; i<32*1024; i+=stride){ ac[i]=0.f; dc[i]=0.f; AH0[i]=0; AH1[i]=0; DH0[i]=0; DH1[i]=0; }
  for (int i=g0; i<32*512;  i+=stride){ CTX[i]=0; }
  for (int i=g0; i<32*400;  i+=stride){ aw[i]=0.f; awc[i]=0.f; }
}

// ---------------- fused prenet: two layers, 64 rows per block ----------------
__global__ __launch_bounds__(256) void k_prenet(
  const float* __restrict__ dec_inp, const float* __restrict__ w1, const float* __restrict__ w2,
  ushortT* __restrict__ preo,
  uint32_t k1a, uint32_t k1b, uint32_t k2a, uint32_t k2b)
{
  __shared__ ushortT Xs[64*96];     // 12 KB
  __shared__ ushortT H1s[64*256];   // 32 KB
  int tid=threadIdx.x, lane=tid&63, wv=tid>>6, quad=lane>>4, nl=lane&15;
  int r0 = blockIdx.x*64;           // rows = s*32 + b
  for (int i=tid; i<64*96; i+=256){
    int rr=i/96, k=i-rr*96; int row=r0+rr; int s=row>>5, b=row&31;
    float v=0.f;
    if (k<80 && s>0) v = dec_inp[((size_t)b*80+k)*500 + (s-1)];
    Xs[i]=f2bf(v);
  }
  __syncthreads();
  f4v acc[4][4];
  #pragma unroll
  for (int mt=0;mt<4;++mt)
    #pragma unroll
    for (int nt=0;nt<4;++nt) acc[mt][nt]=(f4v){0,0,0,0};
  // layer 1: K=80 padded to 96
  for (int kb=0;kb<3;++kb){
    int c0 = kb*32 + quad*8;
    s8v a[4];
    #pragma unroll
    for (int mt=0;mt<4;++mt) a[mt]=*(const s8v*)(Xs + (mt*16+nl)*96 + c0);
    #pragma unroll
    for (int nt=0;nt<4;++nt){
      int rown = wv*64+nt*16+nl;
      s8v bb;
      if (c0 < 80) bb = pack8(w1 + (size_t)rown*80 + c0);
      else { s8v z={0,0,0,0,0,0,0,0}; bb=z; }
      #pragma unroll
      for (int mt=0;mt<4;++mt) acc[mt][nt]=mfma16(a[mt],bb,acc[mt][nt]);
    }
  }
  #pragma unroll
  for (int mt=0;mt<4;++mt)
    #pragma unroll
    for (int nt=0;nt<4;++nt)
      #pragma unroll
      for (int r=0;r<4;++r){
        int mloc = mt*16+quad*4+r;
        int col  = wv*64+nt*16+nl;
        float v = acc[mt][nt][r]; v = v>0.f? v:0.f;
        uint32_t fidx = (uint32_t)(r0+mloc)*256u + (uint32_t)col;
        v = (part_unif(k1a,k1b,fidx) < 0.5f) ? v*2.0f : 0.0f;
        H1s[mloc*256+col]=f2bf(v);
      }
  __syncthreads();
  #pragma unroll
  for (int mt=0;mt<4;++mt)
    #pragma unroll
    for (int nt=0;nt<4;++nt) acc[mt][nt]=(f4v){0,0,0,0};
  // layer 2: K=256
  for (int kb=0;kb<8;++kb){
    int c0 = kb*32 + quad*8;
    s8v a[4];
    #pragma unroll
    for (int mt=0;mt<4;++mt) a[mt]=*(const s8v*)(H1s + (mt*16+nl)*256 + c0);
    #pragma unroll
    for (int nt=0;nt<4;++nt){
      int rown = wv*64+nt*16+nl;
      s8v bb = pack8(w2 + (size_t)rown*256 + c0);
      #pragma unroll
      for (int mt=0;mt<4;++mt) acc[mt][nt]=mfma16(a[mt],bb,acc[mt][nt]);
    }
  }
  #pragma unroll
  for (int mt=0;mt<4;++mt)
    #pragma unroll
    for (int nt=0;nt<4;++nt)
      #pragma unroll
      for (int r=0;r<4;++r){
        int mloc = mt*16+quad*4+r;
        int col  = wv*64+nt*16+nl;
        float v = acc[mt][nt][r]; v = v>0.f? v:0.f;
        uint32_t fidx = (uint32_t)(r0+mloc)*256u + (uint32_t)col;
        v = (part_unif(k2a,k2b,fidx) < 0.5f) ? v*2.0f : 0.0f;
        preo[(size_t)(r0+mloc)*256+col]=f2bf(v);
      }
}

// ---------------- processed_memory: fp32 VALU GEMM (one-shot) ----------------
__global__ __launch_bounds__(256) void k_pm(
  const float* __restrict__ memory, const float* __restrict__ mw, float* __restrict__ pm)
{
  int row = blockIdx.x*2 + (threadIdx.x>>7);
  int col = threadIdx.x & 127;
  const float* mr = memory + (size_t)row*512;
  const float* wr = mw + (size_t)col*512;
  float acc=0.f;
  for (int k=0;k<512;k+=4){
    float4 a=*(const float4*)(mr+k), b=*(const float4*)(wr+k);
    acc += a.x*b.x + a.y*b.y + a.z*b.z + a.w*b.w;
  }
  pm[(size_t)row*128+col]=acc;
}

// ---------------- A: att-LSTM (blocks 0..63) + projection of step t-1 (64..69) ----------------
__global__ __launch_bounds__(256) void k_A(int t,
  const ushortT* __restrict__ Wai, const ushortT* __restrict__ Wah,
  const float* __restrict__ abih, const float* __restrict__ abhh,
  const ushortT* __restrict__ preo,
  const ushortT* __restrict__ AHp, ushortT* __restrict__ AHn,
  const ushortT* __restrict__ CTX, float* __restrict__ ac,
  const ushortT* __restrict__ Wpg, const float* __restrict__ pjb, const float* __restrict__ gb,
  const ushortT* __restrict__ DHd,
  float* __restrict__ out_mel, float* __restrict__ out_gate,
  uint32_t k3a, uint32_t k3b)
{
  __shared__ float gbuf[4][32][17];
  __shared__ float dsum[2][32][16];
  int tid=threadIdx.x, lane=tid&63, wv=tid>>6, quad=lane>>4, nl=lane&15;
  if (blockIdx.x < 64){
    if (t >= TOUT) return;
    int u0 = blockIdx.x*16;
    int rown = wv*1024 + u0 + nl;                 // gate wv, unit u0+nl
    const ushortT* bh = Wah + (size_t)rown*1024 + quad*8;
    const ushortT* bx = Wai + (size_t)rown*768  + quad*8;
    const ushortT* a0 = AHp + (size_t)nl*1024 + quad*8;  const ushortT* a1 = a0 + 16*1024;
    const ushortT* c0p= CTX + (size_t)nl*512  + quad*8;  const ushortT* c1p= c0p + 16*512;
    const ushortT* p0 = preo + ((size_t)t*32 + nl)*256 + quad*8; const ushortT* p1 = p0 + 16*256;
    f4v acc0={0,0,0,0}, acc1={0,0,0,0};
    for (int kb=0;kb<32;++kb){ s8v bb=*(const s8v*)(bh+kb*32);
      acc0=mfma16(*(const s8v*)(a0+kb*32),bb,acc0); acc1=mfma16(*(const s8v*)(a1+kb*32),bb,acc1); }
    for (int kb=0;kb<8;++kb){ s8v bb=*(const s8v*)(bx+kb*32);           // din cols 0..255
      acc0=mfma16(*(const s8v*)(p0+kb*32),bb,acc0); acc1=mfma16(*(const s8v*)(p1+kb*32),bb,acc1); }
    for (int kb=0;kb<16;++kb){ s8v bb=*(const s8v*)(bx+256+kb*32);      // ctx cols 256..767
      acc0=mfma16(*(const s8v*)(c0p+kb*32),bb,acc0); acc1=mfma16(*(const s8v*)(c1p+kb*32),bb,acc1); }
    #pragma unroll
    for (int r=0;r<4;++r){ gbuf[wv][quad*4+r][nl]=acc0[r]; gbuf[wv][quad*4+r+16][nl]=acc1[r]; }
    __syncthreads();
    for (int idx=tid; idx<512; idx+=256){
      int b=idx&31, ul=idx>>5; int u=u0+ul;
      float gi=gbuf[0][b][ul]+abih[u]       +abhh[u];
      float gf=gbuf[1][b][ul]+abih[1024+u]  +abhh[1024+u];
      float gg=gbuf[2][b][ul]+abih[2048+u]  +abhh[2048+u];
      float go=gbuf[3][b][ul]+abih[3072+u]  +abhh[3072+u];
      float cp=ac[b*1024+u];
      float c2=sigm(gf)*cp + sigm(gi)*tanhf(gg);
      float h =sigm(go)*tanhf(c2);
      uint32_t fidx=((uint32_t)(t*32+b))*1024u+(uint32_t)u;
      h = (part_unif(k3a,k3b,fidx) < 0.9f) ? h*(1.0f/0.9f) : 0.0f;
      ac[b*1024+u]=c2;
      AHn[b*1024+u]=f2bf(h);
    }
  } else {
    if (t == 0) return;
    int td = t-1;
    int wgd = blockIdx.x - 64;            // 0..5, rows rb..rb+15 of [proj(80)|gate(1)|pad]
    int rb = wgd*16;
    int mt = wv&1, kh = wv>>1;
    int mrow = nl + mt*16;
    const ushortT* br  = Wpg + (size_t)(rb+nl)*1536 + quad*8;
    const ushortT* dhp = DHd + (size_t)mrow*1024 + quad*8;
    const ushortT* cxp = CTX + (size_t)mrow*512  + quad*8;
    f4v acc={0,0,0,0};
    for (int kb=0;kb<24;++kb){
      int kk = kh*768 + kb*32;
      s8v aa = (kk < 1024) ? *(const s8v*)(dhp + kk) : *(const s8v*)(cxp + (kk-1024));
      s8v bb = *(const s8v*)(br + kk);
      acc = mfma16(aa,bb,acc);
    }
    #pragma unroll
    for (int r=0;r<4;++r) dsum[kh][mt*16+quad*4+r][nl]=acc[r];
    __syncthreads();
    for (int idx=tid; idx<512; idx+=256){
      int m=idx>>4, n=idx&15;
      float v = dsum[0][m][n] + dsum[1][m][n];
      int r = rb + n;
      if (r < 80){
        v += pjb[r];
        out_mel[(size_t)(m*80+r)*500 + td] = v;
      } else if (r == 80){
        v += gb[0];
        out_gate[(size_t)m*500 + td] = v;
      }
    }
  }
}

// ---------------- B1: location conv + energies, grid = 32 b x 4 t-chunks ----------------
__global__ __launch_bounds__(256) void k_B1(int t,
  const ushortT* __restrict__ AHc, const float* __restrict__ qw,
  const float* __restrict__ lcw, const float* __restrict__ llw,
  const float* __restrict__ vw,
  const float* __restrict__ aw, const float* __restrict__ awc,
  const float* __restrict__ pm, const int* __restrict__ mlen,
  float* __restrict__ ebuf)
{
  int bx=blockIdx.x; int b=bx>>2, ch=bx&3; int t0=ch*100;
  int tid=threadIdx.x;
  __shared__ float ahl[1024];
  __shared__ float awp[130], awcp[130];
  __shared__ float cw0[992], cw1[992];
  __shared__ float lw[128*33];
  __shared__ float vv[128];
  __shared__ float pqs[128];
  __shared__ float pq2[256];
  __shared__ float locl[3200];
  __shared__ float epart[200];
  for (int i=tid;i<1024;i+=256) ahl[i]=bf2f(AHc[b*1024+i]);
  for (int i=tid;i<130;i+=256){
    int tt=t0-15+i; float a=0.f,c=0.f;
    if (tt>=0 && tt<TIN){ a=aw[b*TIN+tt]; c=awc[b*TIN+tt]; }
    awp[i]=a; awcp[i]=c;
  }
  for (int i=tid;i<992;i+=256){
    int f=i/31, j=i-f*31;
    cw0[i]=lcw[(f*2+0)*31+j];
    cw1[i]=lcw[(f*2+1)*31+j];
  }
  for (int i=tid;i<4096;i+=256){ int a=i>>5,f=i&31; lw[a*33+f]=llw[i]; }
  if (tid<128) vv[tid]=vw[tid];
  __syncthreads();
  { // pq = query_w @ ah   (redundant per chunk; qw stays L2-hot)
    int a=tid&127, half=tid>>7;
    const float* qr = qw + (size_t)a*1024 + half*512;
    const float* ap = ahl + half*512;
    float acc=0.f;
    for (int u=0;u<512;u+=4){
      float4 q = *(const float4*)(qr+u);
      acc += q.x*ap[u+0] + q.y*ap[u+1] + q.z*ap[u+2] + q.w*ap[u+3];
    }
    pq2[tid]=acc;
  }
  __syncthreads();
  if (tid<128) pqs[tid]=pq2[tid]+pq2[tid+128];
  __syncthreads();
  for (int it=tid; it<3200; it+=256){
    int tl=it>>5, f=it&31;
    const float* c0=cw0+f*31; const float* c1=cw1+f*31;
    float s=0.f;
    #pragma unroll
    for (int j=0;j<31;++j) s += awp[tl+j]*c0[j] + awcp[tl+j]*c1[j];
    locl[tl*32+f]=s;
  }
  __syncthreads();
  {
    int a=tid&127, g=tid>>7, wid=tid>>6;
    const float* lwa = lw + a*33;
    for (int tl=g; tl<100; tl+=2){
      const float* lt = locl + tl*32;
      float l2=0.f;
      #pragma unroll
      for (int f=0;f<32;++f) l2 += lt[f]*lwa[f];
      float x = pqs[a] + l2 + pm[((size_t)b*TIN + (t0+tl))*128 + a];
      float cv = vv[a]*tanhf(x);
      #pragma unroll
      for (int o=32;o>0;o>>=1) cv += __shfl_xor(cv,o);
      if ((tid&63)==0) epart[tl*2+(wid&1)]=cv;
    }
  }
  __syncthreads();
  if (tid<100){
    int tg=t0+tid;
    float e = epart[tid*2]+epart[tid*2+1];
    if (tg >= mlen[b]) e = -__builtin_inff();
    ebuf[b*TIN+tg]=e;
  }
}

// ---------------- B2: softmax + context, grid = 32 ----------------
__global__ __launch_bounds__(256) void k_B2(int t,
  const float* __restrict__ ebuf, const float* __restrict__ memory,
  float* __restrict__ aw, float* __restrict__ awc,
  ushortT* __restrict__ CTX, float* __restrict__ out_align)
{
  int b=blockIdx.x, tid=threadIdx.x, wid=tid>>6;
  __shared__ float p[400];
  __shared__ float red[8];
  float lm = -__builtin_inff();
  for (int i=tid;i<400;i+=256){ float v=ebuf[b*TIN+i]; p[i]=v; lm=fmaxf(lm,v); }
  #pragma unroll
  for (int o=32;o>0;o>>=1) lm=fmaxf(lm,__shfl_xor(lm,o));
  if ((tid&63)==0) red[wid]=lm;
  __syncthreads();
  float mx = fmaxf(fmaxf(red[0],red[1]),fmaxf(red[2],red[3]));
  if (!(mx > -__builtin_inff())) mx = 0.f;   // guard: degenerate row -> zeros, not NaN
  float ls=0.f;
  for (int i=tid;i<400;i+=256){ float pe=__expf(p[i]-mx); p[i]=pe; ls+=pe; }
  #pragma unroll
  for (int o=32;o>0;o>>=1) ls += __shfl_xor(ls,o);
  if ((tid&63)==0) red[4+wid]=ls;
  __syncthreads();
  float S = red[4]+red[5]+red[6]+red[7];
  float rS = (S>0.f) ? 1.0f/S : 0.f;
  for (int i=tid;i<400;i+=256){
    float a2 = p[i]*rS; p[i]=a2;
    aw[b*TIN+i]=a2;
    awc[b*TIN+i]+=a2;
    out_align[((size_t)b*500 + t)*400 + i]=a2;
  }
  __syncthreads();
  int d0 = tid*2;
  float c0=0.f,c1=0.f;
  const float* mb = memory + (size_t)b*TIN*512;
  for (int tt=0; tt<TIN; ++tt){
    float w = p[tt];
    float2 mm = *(const float2*)(mb + (size_t)tt*512 + d0);
    c0 += w*mm.x; c1 += w*mm.y;
  }
  CTX[b*512+d0]  =f2bf(c0);
  CTX[b*512+d0+1]=f2bf(c1);
}

// ---------------- C: decoder LSTM ----------------
__global__ __launch_bounds__(256) void k_C(int t,
  const ushortT* __restrict__ Wdi, const ushortT* __restrict__ Wdh,
  const float* __restrict__ dbih, const float* __restrict__ dbhh,
  const ushortT* __restrict__ AHc, const ushortT* __restrict__ CTX,
  const ushortT* __restrict__ DHp, ushortT* __restrict__ DHn,
  float* __restrict__ dc, uint32_t k4a, uint32_t k4b)
{
  __shared__ float gbuf[4][32][17];
  int tid=threadIdx.x, lane=tid&63, wv=tid>>6, quad=lane>>4, nl=lane&15;
  int u0 = blockIdx.x*16;
  int rown = wv*1024 + u0 + nl;
  const ushortT* bh = Wdh + (size_t)rown*1024 + quad*8;
  const ushortT* bx = Wdi + (size_t)rown*1536 + quad*8;
  const ushortT* a0 = AHc + (size_t)nl*1024 + quad*8;  const ushortT* a1 = a0 + 16*1024;
  const ushortT* c0p= CTX + (size_t)nl*512  + quad*8;  const ushortT* c1p= c0p + 16*512;
  const ushortT* d0 = DHp + (size_t)nl*1024 + quad*8;  const ushortT* d1 = d0 + 16*1024;
  f4v acc0={0,0,0,0}, acc1={0,0,0,0};
  for (int kb=0;kb<32;++kb){ s8v bb=*(const s8v*)(bx+kb*32);          // ah cols 0..1023
    acc0=mfma16(*(const s8v*)(a0+kb*32),bb,acc0); acc1=mfma16(*(const s8v*)(a1+kb*32),bb,acc1); }
  for (int kb=0;kb<16;++kb){ s8v bb=*(const s8v*)(bx+1024+kb*32);     // ctx cols 1024..1535
    acc0=mfma16(*(const s8v*)(c0p+kb*32),bb,acc0); acc1=mfma16(*(const s8v*)(c1p+kb*32),bb,acc1); }
  for (int kb=0;kb<32;++kb){ s8v bb=*(const s8v*)(bh+kb*32);          // hidden
    acc0=mfma16(*(const s8v*)(d0+kb*32),bb,acc0); acc1=mfma16(*(const s8v*)(d1+kb*32),bb,acc1); }
  #pragma unroll
  for (int r=0;r<4;++r){ gbuf[wv][quad*4+r][nl]=acc0[r]; gbuf[wv][quad*4+r+16][nl]=acc1[r]; }
  __syncthreads();
  for (int idx=tid; idx<512; idx+=256){
    int b=idx&31, ul=idx>>5; int u=u0+ul;
    float gi=gbuf[0][b][ul]+dbih[u]      +dbhh[u];
    float gf=gbuf[1][b][ul]+dbih[1024+u] +dbhh[1024+u];
    float gg=gbuf[2][b][ul]+dbih[2048+u] +dbhh[2048+u];
    float go=gbuf[3][b][ul]+dbih[3072+u] +dbhh[3072+u];
    float cp=dc[b*1024+u];
    float c2=sigm(gf)*cp + sigm(gi)*tanhf(gg);
    float h =sigm(go)*tanhf(c2);
    uint32_t fidx=((uint32_t)(t*32+b))*1024u+(uint32_t)u;
    h = (part_unif(k4a,k4b,fidx) < 0.9f) ? h*(1.0f/0.9f) : 0.0f;
    dc[b*1024+u]=c2;
    DHn[b*1024+u]=f2bf(h);
  }
}

// ---------------- host ----------------
extern "C" void kernel_launch(void* const* d_in, const int* in_sizes, int n_in,
                              void* d_out, int out_size, void* d_ws, size_t ws_size,
                              hipStream_t stream) {
  (void)in_sizes; (void)n_in; (void)out_size; (void)ws_size;
  const float* memory  = (const float*)d_in[0];
  const float* dec_inp = (const float*)d_in[1];
  const int*   mlen    = (const int*)d_in[2];
  const float* pw1     = (const float*)d_in[3];
  const float* pw2     = (const float*)d_in[4];
  const float* awih    = (const float*)d_in[5];
  const float* awhh    = (const float*)d_in[6];
  const float* abih    = (const float*)d_in[7];
  const float* abhh    = (const float*)d_in[8];
  const float* qw      = (const float*)d_in[9];
  const float* mw      = (const float*)d_in[10];
  const float* vw      = (const float*)d_in[11];
  const float* lcw     = (const float*)d_in[12];
  const float* llw     = (const float*)d_in[13];
  const float* dwih    = (const float*)d_in[14];
  const float* dwhh    = (const float*)d_in[15];
  const float* dbih    = (const float*)d_in[16];
  const float* dbhh    = (const float*)d_in[17];
  const float* pjw     = (const float*)d_in[18];
  const float* pjb     = (const float*)d_in[19];
  const float* gw      = (const float*)d_in[20];
  const float* gb      = (const float*)d_in[21];

  char* w = (char*)d_ws;
  size_t off=0;
  auto alloc = [&](size_t n)->char*{ char* p=w+off; off=(off+n+255)&~(size_t)255; return p; };
  ushortT* Wai = (ushortT*)alloc(4096UL*768*2);
  ushortT* Wah = (ushortT*)alloc(4096UL*1024*2);
  ushortT* Wdi = (ushortT*)alloc(4096UL*1536*2);
  ushortT* Wdh = (ushortT*)alloc(4096UL*1024*2);
  ushortT* Wpg = (ushortT*)alloc(96UL*1536*2);
  ushortT* preo= (ushortT*)alloc(16000UL*256*2);
  float*   pm  = (float*)alloc(12800UL*128*4);
  ushortT* AH0 = (ushortT*)alloc(32UL*1024*2);
  ushortT* AH1 = (ushortT*)alloc(32UL*1024*2);
  ushortT* DH0 = (ushortT*)alloc(32UL*1024*2);
  ushortT* DH1 = (ushortT*)alloc(32UL*1024*2);
  ushortT* CTX = (ushortT*)alloc(32UL*512*2);
  float*   ac  = (float*)alloc(32UL*1024*4);
  float*   dc  = (float*)alloc(32UL*1024*4);
  float*   aw  = (float*)alloc(12800UL*4);
  float*   awc = (float*)alloc(12800UL*4);
  float*   ebuf= (float*)alloc(12800UL*4);

  // JAX partitionable split(key(42), 4): subkey_i = threefry((0,42), (0, i)) -> (o0, o1)
  uint32_t K[4][2];
  for (uint32_t i=0;i<4;++i) tf2x32(0u,42u,0u,i,&K[i][0],&K[i][1]);
  // K[0]=prenet layer1, K[1]=prenet layer2, K[2]=att_drop, K[3]=dec_drop

  float* out_mel   = (float*)d_out;
  float* out_gate  = out_mel + 1280000;
  float* out_align = out_mel + 1296000;

  k_setup<<<1024,256,0,stream>>>(awih,awhh,dwih,dwhh,pjw,gw,
                                 Wai,Wah,Wdi,Wdh,Wpg,AH0,AH1,DH0,DH1,CTX,ac,dc,aw,awc);
  k_prenet<<<250,256,0,stream>>>(dec_inp, pw1, pw2, preo, K[0][0],K[0][1], K[1][0],K[1][1]);
  k_pm<<<6400,256,0,stream>>>(memory, mw, pm);

  for (int t=0; t<=TOUT; ++t){
    const ushortT* AHp = (t&1)? AH1:AH0;
    ushortT*       AHn = (t&1)? AH0:AH1;
    const ushortT* DHp = (t&1)? DH1:DH0;
    ushortT*       DHn = (t&1)? DH0:DH1;
    k_A<<<70,256,0,stream>>>(t, Wai, Wah, abih, abhh, preo, AHp, AHn, CTX, ac,
                             Wpg, pjb, gb, DHp, out_mel, out_gate, K[2][0],K[2][1]);
    if (t < TOUT){
      k_B1<<<128,256,0,stream>>>(t, AHn, qw, lcw, llw, vw, aw, awc, pm, mlen, ebuf);
      k_B2<<<32,256,0,stream>>>(t, ebuf, memory, aw, awc, CTX, out_align);
      k_C<<<64,256,0,stream>>>(t, Wdi, Wdh, dbih, dbhh, AHn, CTX, DHp, DHn, dc, K[3][0],K[3][1]);
    }
  }
}